// Round 5
// baseline (642.110 us; speedup 1.0000x reference)
//
#include <hip/hip_runtime.h>
#include <math.h>

// MFMA fragment types (gfx950, 16x16x32 f16: 8 halves A/B, 4 floats C/D)
typedef _Float16 v8h  __attribute__((ext_vector_type(8)));
typedef float    fx4  __attribute__((ext_vector_type(4)));

#define S1_FRAGS 18   // 6 n-tiles * 3 k-steps  (DCT matrix, 96x96)
#define S2_FRAGS 36   // 12 n-tiles * 3 k-steps (W1, 192x96)
#define S3_FRAGS 36   // 6 n-tiles * 6 k-steps  (W2, 96x192)
// each frag: 64 lanes * 16B = 1024 B; total ws use = 90 KB

// Pre-gather B-fragments in MFMA lane order so the main kernel loads each
// fragment as one perfectly-coalesced global_load_dwordx4 (base + lane*16).
// B-frag layout (verified m89/m91): lane L holds B[k=(L>>4)*8+j][n=L&15].
__global__ void prep_frags(const float* __restrict__ W1,
                           const float* __restrict__ W2,
                           v8h* __restrict__ ws) {
    const int f    = blockIdx.x;    // 0..89
    const int lane = threadIdx.x;   // 0..63
    v8h v;
    if (f < S1_FRAGS) {
        const int t = f / 3, s = f % 3;
        const int n  = t * 16 + (lane & 15);        // DCT output index k_out
        const int k0 = s * 32 + (lane >> 4) * 8;    // input index i
#pragma unroll
        for (int j = 0; j < 8; ++j) {
            const int i = k0 + j;
            // D[k,i] = 2*cos(pi*(2i+1)*k / 192)
            const float ang = 3.14159265358979323846f * (float)((2 * i + 1) * n) / 192.0f;
            v[j] = (_Float16)(2.0f * cosf(ang));
        }
    } else if (f < S1_FRAGS + S2_FRAGS) {
        const int g = f - S1_FRAGS;
        const int t = g / 3, s = g % 3;
        const int n  = t * 16 + (lane & 15);
        const int k0 = s * 32 + (lane >> 4) * 8;
#pragma unroll
        for (int j = 0; j < 8; ++j) v[j] = (_Float16)W1[n * 96 + k0 + j];
    } else {
        const int g = f - S1_FRAGS - S2_FRAGS;
        const int t = g / 6, s = g % 6;
        const int n  = t * 16 + (lane & 15);
        const int k0 = s * 32 + (lane >> 4) * 8;
#pragma unroll
        for (int j = 0; j < 8; ++j) v[j] = (_Float16)W2[n * 192 + k0 + j];
    }
    ws[f * 64 + lane] = v;
}

// Per-wave 6400 B band buffer, time-shared by three layouts (never live
// simultaneously; per-wave DS pipe is in-order — WAR/RAW within a wave is
// safe, empirically validated by the round-4 union kernel — and asm memory
// barriers pin source order across layout transitions):
//   LN1 out  : f16 [16][LDA=104]  (3328 B)
//   relu out : f16 [16][LDH=200]  (6400 B)
//   lr_weight: f32 [16][LDW=100]  (6400 B)  <- epilogue transpose C->A layout
// 4 bands * 6400 B = 25600 B/block -> 6 blocks/CU.
#define LDA 104
#define LDH 200
#define LDW 100
#define BANDB 6400

__global__ __launch_bounds__(256, 6)
void fused_dct_mlp(const float* __restrict__ x,
                   const float* __restrict__ gamma,
                   const float* __restrict__ beta,
                   const v8h* __restrict__ wf,
                   float* __restrict__ out) {
    __shared__ __align__(16) unsigned char Uraw[4][BANDB];

    const int tid  = threadIdx.x;
    const int lane = tid & 63;
    const int wave = tid >> 6;
    const int m0   = wave * 16;         // band base row (block-local)
    const int lr_  = lane & 15;         // A-row / C-col within tile
    const int lk   = lane >> 4;         // k-chunk selector / C-row-group

    _Float16* band  = (_Float16*)Uraw[wave];
    float*    bandf = (float*)Uraw[wave];

    const long row0 = (long)blockIdx.x * 64;
    const float* arow = x + (row0 + m0 + lr_) * 96;   // this lane's stage-1 A row

    // LN affine params: identical column pattern in LN1 and LN2 -> load once.
    float gv[6], bv[6];
#pragma unroll
    for (int t = 0; t < 6; ++t) {
        gv[t] = gamma[t * 16 + lr_];
        bv[t] = beta[t * 16 + lr_];
    }

    // ---------------- stage 1: dct = x @ D^T ----------------
    // Keep the f32 x values in registers (24 VGPRs): the epilogue multiplies
    // by exactly these elements -> NO global x re-read (round-4 showed the
    // re-read misses L2 at 6 blocks/CU: FETCH 188->366 MB).
    fx4 ax0[3], ax1[3];
    fx4 acc1[6];
#pragma unroll
    for (int t = 0; t < 6; ++t) acc1[t] = (fx4){0.f, 0.f, 0.f, 0.f};
#pragma unroll
    for (int s = 0; s < 3; ++s) {
        // A-frag: lane holds A[m=lr_][k = s*32 + lk*8 + j], straight from global fp32
        const float* ap = arow + s * 32 + lk * 8;
        ax0[s] = *(const fx4*)ap;
        ax1[s] = *(const fx4*)(ap + 4);
        v8h a;
#pragma unroll
        for (int j = 0; j < 4; ++j) { a[j] = (_Float16)ax0[s][j]; a[4 + j] = (_Float16)ax1[s][j]; }
#pragma unroll
        for (int t = 0; t < 6; ++t) {
            v8h b = wf[(t * 3 + s) * 64 + lane];
            acc1[t] = __builtin_amdgcn_mfma_f32_16x16x32_f16(a, b, acc1[t], 0, 0, 0);
        }
    }

    // ---- LN1 straight from C-registers ----
    // C layout: lane holds band-local rows lk*4+r (r=0..3) at col t*16+lr_.
    {
        float sum[4] = {0, 0, 0, 0}, sq[4] = {0, 0, 0, 0};
#pragma unroll
        for (int t = 0; t < 6; ++t)
#pragma unroll
            for (int r = 0; r < 4; ++r) { float v = acc1[t][r]; sum[r] += v; sq[r] += v * v; }
#pragma unroll
        for (int m = 1; m <= 8; m <<= 1)
#pragma unroll
            for (int r = 0; r < 4; ++r) {
                sum[r] += __shfl_xor(sum[r], m, 64);
                sq[r]  += __shfl_xor(sq[r],  m, 64);
            }
        float mu[4], rs[4];
#pragma unroll
        for (int r = 0; r < 4; ++r) {
            mu[r] = sum[r] * (1.0f / 96.0f);
            float var = sq[r] * (1.0f / 96.0f) - mu[r] * mu[r];
            rs[r] = rsqrtf(var + 1e-6f);
        }
#pragma unroll
        for (int t = 0; t < 6; ++t) {
            const int col = t * 16 + lr_;
#pragma unroll
            for (int r = 0; r < 4; ++r) {
                float w = (acc1[t][r] - mu[r]) * rs[r] * gv[t] + bv[t];
                band[(lk * 4 + r) * LDA + col] = (_Float16)w;
            }
        }
    }

    // ---------------- stage 2: h = relu(lr @ W1^T) ----------------
    fx4 acc2[12];
#pragma unroll
    for (int t = 0; t < 12; ++t) acc2[t] = (fx4){0.f, 0.f, 0.f, 0.f};
#pragma unroll
    for (int s = 0; s < 3; ++s) {
        v8h a = *(const v8h*)&band[lr_ * LDA + s * 32 + lk * 8];
        const v8h* bp = wf + S1_FRAGS * 64;
#pragma unroll
        for (int t = 0; t < 12; ++t) {
            v8h b = bp[(t * 3 + s) * 64 + lane];
            acc2[t] = __builtin_amdgcn_mfma_f32_16x16x32_f16(a, b, acc2[t], 0, 0, 0);
        }
    }
    asm volatile("" ::: "memory");   // LN1-layout reads before relu-layout overwrite
#pragma unroll
    for (int t = 0; t < 12; ++t) {
        const int col = t * 16 + lr_;
#pragma unroll
        for (int r = 0; r < 4; ++r)
            band[(lk * 4 + r) * LDH + col] = (_Float16)fmaxf(acc2[t][r], 0.0f);
    }

    // ---------------- stage 3: s = sigmoid(h @ W2^T) ----------------
    fx4 acc3[6];
#pragma unroll
    for (int t = 0; t < 6; ++t) acc3[t] = (fx4){0.f, 0.f, 0.f, 0.f};
#pragma unroll
    for (int s = 0; s < 6; ++s) {
        v8h a = *(const v8h*)&band[lr_ * LDH + s * 32 + lk * 8];
        const v8h* bp = wf + (S1_FRAGS + S2_FRAGS) * 64;
#pragma unroll
        for (int t = 0; t < 6; ++t) {
            v8h b = bp[(t * 6 + s) * 64 + lane];
            acc3[t] = __builtin_amdgcn_mfma_f32_16x16x32_f16(a, b, acc3[t], 0, 0, 0);
        }
    }
    // sigmoid: single v_rcp_f32 (~1 ulp) instead of the ~9-instr precise div
#pragma unroll
    for (int t = 0; t < 6; ++t)
#pragma unroll
        for (int r = 0; r < 4; ++r)
            acc3[t][r] = __builtin_amdgcn_rcpf(1.0f + __expf(-acc3[t][r]));

    // ---- LN2 from registers; stash w (f32) into band buffer (C layout) ----
    {
        float sum[4] = {0, 0, 0, 0}, sq[4] = {0, 0, 0, 0};
#pragma unroll
        for (int t = 0; t < 6; ++t)
#pragma unroll
            for (int r = 0; r < 4; ++r) { float v = acc3[t][r]; sum[r] += v; sq[r] += v * v; }
#pragma unroll
        for (int m = 1; m <= 8; m <<= 1)
#pragma unroll
            for (int r = 0; r < 4; ++r) {
                sum[r] += __shfl_xor(sum[r], m, 64);
                sq[r]  += __shfl_xor(sq[r],  m, 64);
            }
        float mu[4], rs[4];
#pragma unroll
        for (int r = 0; r < 4; ++r) {
            mu[r] = sum[r] * (1.0f / 96.0f);
            float var = sq[r] * (1.0f / 96.0f) - mu[r] * mu[r];
            rs[r] = rsqrtf(var + 1e-6f);
        }
        asm volatile("" ::: "memory");   // relu-layout reads before f32-w overwrite
#pragma unroll
        for (int t = 0; t < 6; ++t) {
            const int col = t * 16 + lr_;
#pragma unroll
            for (int r = 0; r < 4; ++r) {
                float w = (acc3[t][r] - mu[r]) * rs[r] * gv[t] + bv[t];
                bandf[(lk * 4 + r) * LDW + col] = w;
            }
        }
    }
    asm volatile("" ::: "memory");   // w writes before w reads (layout transpose)

    // ---- epilogue: out = x * w, A-layout, x from registers ----
    // Lane reads back its OWN row (lr_) of w and multiplies by the x values
    // it already holds. Per s-step the wave stores 128 B contiguous per row
    // x 16 rows -> complete cache lines, no read-modify-write (round-4's
    // scattered 4 B stores caused WRITE 196->536 MB).
    {
        const long rowbase = (row0 + m0 + lr_) * 96;
#pragma unroll
        for (int s = 0; s < 3; ++s) {
            const int c0 = s * 32 + lk * 8;
            fx4 w0 = *(const fx4*)&bandf[lr_ * LDW + c0];
            fx4 w1 = *(const fx4*)&bandf[lr_ * LDW + c0 + 4];
            fx4 o0 = ax0[s] * w0;
            fx4 o1 = ax1[s] * w1;
            *(fx4*)&out[rowbase + c0]     = o0;
            *(fx4*)&out[rowbase + c0 + 4] = o1;
        }
    }
}

extern "C" void kernel_launch(void* const* d_in, const int* in_sizes, int n_in,
                              void* d_out, int out_size, void* d_ws, size_t ws_size,
                              hipStream_t stream) {
    const float* x     = (const float*)d_in[0];
    const float* W1    = (const float*)d_in[1];
    const float* W2    = (const float*)d_in[2];
    const float* gamma = (const float*)d_in[3];
    const float* beta  = (const float*)d_in[4];
    float* out = (float*)d_out;
    v8h* ws = (v8h*)d_ws;   // 90 KB of pre-gathered B-fragments

    prep_frags<<<S1_FRAGS + S2_FRAGS + S3_FRAGS, 64, 0, stream>>>(W1, W2, ws);

    const long rows = (long)in_sizes[0] / 96;   // 524288
    fused_dct_mlp<<<(int)(rows / 64), 256, 0, stream>>>(x, gamma, beta, ws, out);
}

// Round 6
// 437.795 us; speedup vs baseline: 1.4667x; 1.4667x over previous
//
#include <hip/hip_runtime.h>
#include <math.h>

// MFMA fragment types (gfx950, 16x16x32 f16: 8 halves A/B, 4 floats C/D)
typedef _Float16 v8h  __attribute__((ext_vector_type(8)));
typedef float    fx4  __attribute__((ext_vector_type(4)));

#define S1_FRAGS 18   // 6 n-tiles * 3 k-steps  (DCT matrix, 96x96)
#define S2_FRAGS 36   // 12 n-tiles * 3 k-steps (W1, 192x96)
#define S3_FRAGS 36   // 6 n-tiles * 6 k-steps  (W2, 96x192)
// each frag: 64 lanes * 16B = 1024 B; total ws use = 90 KB

// Pre-gather B-fragments in MFMA lane order so the main kernel loads each
// fragment as one perfectly-coalesced global_load_dwordx4 (base + lane*16).
// B-frag layout (verified m89/m91): lane L holds B[k=(L>>4)*8+j][n=L&15].
__global__ void prep_frags(const float* __restrict__ W1,
                           const float* __restrict__ W2,
                           v8h* __restrict__ ws) {
    const int f    = blockIdx.x;    // 0..89
    const int lane = threadIdx.x;   // 0..63
    v8h v;
    if (f < S1_FRAGS) {
        const int t = f / 3, s = f % 3;
        const int n  = t * 16 + (lane & 15);        // DCT output index k_out
        const int k0 = s * 32 + (lane >> 4) * 8;    // input index i
#pragma unroll
        for (int j = 0; j < 8; ++j) {
            const int i = k0 + j;
            // D[k,i] = 2*cos(pi*(2i+1)*k / 192)
            const float ang = 3.14159265358979323846f * (float)((2 * i + 1) * n) / 192.0f;
            v[j] = (_Float16)(2.0f * cosf(ang));
        }
    } else if (f < S1_FRAGS + S2_FRAGS) {
        const int g = f - S1_FRAGS;
        const int t = g / 3, s = g % 3;
        const int n  = t * 16 + (lane & 15);
        const int k0 = s * 32 + (lane >> 4) * 8;
#pragma unroll
        for (int j = 0; j < 8; ++j) v[j] = (_Float16)W1[n * 96 + k0 + j];
    } else {
        const int g = f - S1_FRAGS - S2_FRAGS;
        const int t = g / 6, s = g % 6;
        const int n  = t * 16 + (lane & 15);
        const int k0 = s * 32 + (lane >> 4) * 8;
#pragma unroll
        for (int j = 0; j < 8; ++j) v[j] = (_Float16)W2[n * 192 + k0 + j];
    }
    ws[f * 64 + lane] = v;
}

// ROUND-0 memory structure restored verbatim: two LDS buffers, 38912 B/block
// -> 3-4 blocks/CU. Measured (round 0): FETCH 188 MB / WRITE 196 MB — the
// traffic floor (x once + out once). Rounds 4/5 proved that 6 blocks/CU
// thrashes L2 (F/W up to 440/876 MB). Do NOT raise occupancy on this kernel.
#define LDA 104   // f16 leading dim for lr tile (96+8)
#define LDH 200   // f16 leading dim for h tile (192+8)

// One block = 64 rows, 4 waves; each wave owns a 16-row band. All LDS traffic
// is band-local (rows [m0, m0+16) only), so NO __syncthreads is needed.
__global__ __launch_bounds__(256, 3)
void fused_dct_mlp(const float* __restrict__ x,
                   const float* __restrict__ gamma,
                   const float* __restrict__ beta,
                   const v8h* __restrict__ wf,
                   float* __restrict__ out) {
    __shared__ _Float16 LRB[64][LDA];   // LN1 output (stage-2 A operand)
    __shared__ _Float16 HB[64][LDH];    // relu output (stage-3 A operand)

    const int tid  = threadIdx.x;
    const int lane = tid & 63;
    const int wave = tid >> 6;
    const int m0   = wave * 16;         // band base row (block-local)
    const int lr_  = lane & 15;         // A-row / C-col within tile
    const int lk   = lane >> 4;         // k-chunk selector / C-row-group

    const long row0 = (long)blockIdx.x * 64;
    const float* arow = x + (row0 + m0 + lr_) * 96;   // this lane's stage-1 A row

    // LN affine params: identical column pattern in LN1 and LN2 -> load once.
    float gv[6], bv[6];
#pragma unroll
    for (int t = 0; t < 6; ++t) {
        gv[t] = gamma[t * 16 + lr_];
        bv[t] = beta[t * 16 + lr_];
    }

    // ---------------- stage 1: dct = x @ D^T ----------------
    fx4 acc1[6];
#pragma unroll
    for (int t = 0; t < 6; ++t) acc1[t] = (fx4){0.f, 0.f, 0.f, 0.f};
#pragma unroll
    for (int s = 0; s < 3; ++s) {
        // A-frag: lane holds A[m=lr_][k = s*32 + lk*8 + j], straight from global fp32
        const float* ap = arow + s * 32 + lk * 8;
        fx4 a0 = *(const fx4*)ap;
        fx4 a1 = *(const fx4*)(ap + 4);
        v8h a;
#pragma unroll
        for (int j = 0; j < 4; ++j) { a[j] = (_Float16)a0[j]; a[4 + j] = (_Float16)a1[j]; }
#pragma unroll
        for (int t = 0; t < 6; ++t) {
            v8h b = wf[(t * 3 + s) * 64 + lane];
            acc1[t] = __builtin_amdgcn_mfma_f32_16x16x32_f16(a, b, acc1[t], 0, 0, 0);
        }
    }

    // ---- LN1 straight from C-registers ----
    // C layout: lane holds rows m0+lk*4+r (r=0..3) at col t*16+lr_.
    {
        float sum[4] = {0, 0, 0, 0}, sq[4] = {0, 0, 0, 0};
#pragma unroll
        for (int t = 0; t < 6; ++t)
#pragma unroll
            for (int r = 0; r < 4; ++r) { float v = acc1[t][r]; sum[r] += v; sq[r] += v * v; }
#pragma unroll
        for (int m = 1; m <= 8; m <<= 1)
#pragma unroll
            for (int r = 0; r < 4; ++r) {
                sum[r] += __shfl_xor(sum[r], m, 64);
                sq[r]  += __shfl_xor(sq[r],  m, 64);
            }
        float mu[4], rs[4];
#pragma unroll
        for (int r = 0; r < 4; ++r) {
            mu[r] = sum[r] * (1.0f / 96.0f);
            float var = sq[r] * (1.0f / 96.0f) - mu[r] * mu[r];
            rs[r] = __builtin_amdgcn_rsqf(var + 1e-6f);   // v_rsq_f32, ~1 ulp
        }
#pragma unroll
        for (int t = 0; t < 6; ++t) {
            const int col = t * 16 + lr_;
#pragma unroll
            for (int r = 0; r < 4; ++r) {
                float w = (acc1[t][r] - mu[r]) * rs[r] * gv[t] + bv[t];
                LRB[m0 + lk * 4 + r][col] = (_Float16)w;
            }
        }
    }

    // ---------------- stage 2: h = relu(lr @ W1^T) ----------------
    fx4 acc2[12];
#pragma unroll
    for (int t = 0; t < 12; ++t) acc2[t] = (fx4){0.f, 0.f, 0.f, 0.f};
#pragma unroll
    for (int s = 0; s < 3; ++s) {
        v8h a = *(const v8h*)&LRB[m0 + lr_][s * 32 + lk * 8];
        const v8h* bp = wf + S1_FRAGS * 64;
#pragma unroll
        for (int t = 0; t < 12; ++t) {
            v8h b = bp[(t * 3 + s) * 64 + lane];
            acc2[t] = __builtin_amdgcn_mfma_f32_16x16x32_f16(a, b, acc2[t], 0, 0, 0);
        }
    }
#pragma unroll
    for (int t = 0; t < 12; ++t) {
        const int col = t * 16 + lr_;
#pragma unroll
        for (int r = 0; r < 4; ++r)
            HB[m0 + lk * 4 + r][col] = (_Float16)fmaxf(acc2[t][r], 0.0f);
    }

    // ---------------- stage 3: s = sigmoid(h @ W2^T) ----------------
    fx4 acc3[6];
#pragma unroll
    for (int t = 0; t < 6; ++t) acc3[t] = (fx4){0.f, 0.f, 0.f, 0.f};
#pragma unroll
    for (int s = 0; s < 6; ++s) {
        v8h a = *(const v8h*)&HB[m0 + lr_][s * 32 + lk * 8];
        const v8h* bp = wf + (S1_FRAGS + S2_FRAGS) * 64;
#pragma unroll
        for (int t = 0; t < 6; ++t) {
            v8h b = bp[(t * 6 + s) * 64 + lane];
            acc3[t] = __builtin_amdgcn_mfma_f32_16x16x32_f16(a, b, acc3[t], 0, 0, 0);
        }
    }
    // sigmoid: single v_rcp_f32 (~1 ulp) instead of the ~9-instr precise div
    // (numerically validated round 5: absmax unchanged at 0.0625)
#pragma unroll
    for (int t = 0; t < 6; ++t)
#pragma unroll
        for (int r = 0; r < 4; ++r)
            acc3[t][r] = __builtin_amdgcn_rcpf(1.0f + __expf(-acc3[t][r]));

    // ---- LN2 from registers + final out = x * lr_weight ----
    {
        float sum[4] = {0, 0, 0, 0}, sq[4] = {0, 0, 0, 0};
#pragma unroll
        for (int t = 0; t < 6; ++t)
#pragma unroll
            for (int r = 0; r < 4; ++r) { float v = acc3[t][r]; sum[r] += v; sq[r] += v * v; }
#pragma unroll
        for (int m = 1; m <= 8; m <<= 1)
#pragma unroll
            for (int r = 0; r < 4; ++r) {
                sum[r] += __shfl_xor(sum[r], m, 64);
                sq[r]  += __shfl_xor(sq[r],  m, 64);
            }
        float mu[4], rs[4];
#pragma unroll
        for (int r = 0; r < 4; ++r) {
            mu[r] = sum[r] * (1.0f / 96.0f);
            float var = sq[r] * (1.0f / 96.0f) - mu[r] * mu[r];
            rs[r] = __builtin_amdgcn_rsqf(var + 1e-6f);
        }
#pragma unroll
        for (int t = 0; t < 6; ++t) {
            const int col = t * 16 + lr_;
#pragma unroll
            for (int r = 0; r < 4; ++r) {
                const long grow = row0 + m0 + lk * 4 + r;
                const long off  = grow * 96 + col;
                float w = (acc3[t][r] - mu[r]) * rs[r] * gv[t] + bv[t];
                out[off] = x[off] * w;   // x re-read: L2-hot at 3-4 blocks/CU (measured)
            }
        }
    }
}

extern "C" void kernel_launch(void* const* d_in, const int* in_sizes, int n_in,
                              void* d_out, int out_size, void* d_ws, size_t ws_size,
                              hipStream_t stream) {
    const float* x     = (const float*)d_in[0];
    const float* W1    = (const float*)d_in[1];
    const float* W2    = (const float*)d_in[2];
    const float* gamma = (const float*)d_in[3];
    const float* beta  = (const float*)d_in[4];
    float* out = (float*)d_out;
    v8h* ws = (v8h*)d_ws;   // 90 KB of pre-gathered B-fragments

    prep_frags<<<S1_FRAGS + S2_FRAGS + S3_FRAGS, 64, 0, stream>>>(W1, W2, ws);

    const long rows = (long)in_sizes[0] / 96;   // 524288
    fused_dct_mlp<<<(int)(rows / 64), 256, 0, stream>>>(x, gamma, beta, ws, out);
}